// Round 14
// baseline (108.757 us; speedup 1.0000x reference)
//
#include <hip/hip_runtime.h>
#include <cstdint>
#include <cstddef>

typedef __attribute__((ext_vector_type(8))) short short8v;
typedef __attribute__((ext_vector_type(4))) unsigned uint4v;
typedef __attribute__((ext_vector_type(4))) float floatx4;

#define LIN 568   // weight row length: 1 + 9*63

__device__ __forceinline__ float bf16_to_f32(short s) {
  return __builtin_bit_cast(float, ((unsigned)(unsigned short)s) << 16);
}
// Packed RNE f32->bf16 (2 values / instruction) — same rounding as the old
// prep_weight's manual RNE -> bitwise-identical B fragments.
__device__ __forceinline__ unsigned cvt_pk_bf16(float lo, float hi) {
  unsigned r;
  asm("v_cvt_pk_bf16_f32 %0, %1, %2" : "=v"(r) : "v"(lo), "v"(hi));
  return r;
}
// Cross-lane add via DPP (pure VALU, no ds op).
template<int CTRL>
__device__ __forceinline__ float dpp_add(float v) {
  int y = __builtin_amdgcn_update_dpp(0, __builtin_bit_cast(int, v), CTRL, 0xF, 0xF, true);
  return v + __builtin_bit_cast(float, y);
}

// SINGLE-KERNEL champion: R8 structure with the weight-prep kernel FUSED AWAY.
// B-fragment for (step, nb): lane l holds W[n = nb*16 + (l&15)]
// [k = tap*64 + half*32 + (l>>4)*8 + j], which in w's natural layout is the
// 8 consecutive floats  w[n*568 + tap*63 + half*32 + q*8 + j]  (c==0 time
// column zeroed; it is handled by the rank-1 epilogue). Loaded as 8 scalar
// dwords + 4 cvt_pk (RNE) -> bitwise-identical fragments to the old wfragg,
// with per-nb base pointers hoisted and per-step offsets as immediates.
// This deletes the prep dispatch + one inter-kernel gap, and removes ALL
// workspace use. Everything else is R8 verbatim: T14 issue-early x staging,
// two-phase LDS tile, depth-3 B rotation, DPP Lorentz reduce, LDS-staged
// coalesced output flush.
__launch_bounds__(256, 2)
__global__ void lconv_main(const float* __restrict__ x, const float* __restrict__ w,
                           const float* __restrict__ bias, float* __restrict__ out) {
  // 66560 B: short xt[6*66*72] (57024 B) during compute, then aliased as
  // float ostg[4][4160] for the store-staging epilogue.
  __shared__ __align__(16) char shmem[4 * 4160 * 4];
  __shared__ float tres_s[4 * 64];    // per-wave time-feature row (1 KB)
  short* xt = (short*)shmem;

  const int tid = threadIdx.x;
  const int bb = blockIdx.x >> 4;          // batch 0..31
  const int h0 = (blockIdx.x & 15) << 2;   // first output row of 4-row strip
  const float* xb = x + (size_t)bb * (64 * 64 * 64);

  const int lane = tid & 63;
  const int l15 = lane & 15;
  const int q = lane >> 4;
  const int wv = tid >> 6;   // wave id = strip row

  // ---- issue ALL x staging loads up front (T14 issue-early) ----
  float4 s0[12], s1[12];
#pragma unroll
  for (int i = 0; i < 12; ++i) {
    int idx = i * 256 + tid;       // 0..3071 : rows 0..5 x 64 cols x 8 ch8-groups
    int row = idx >> 9;
    int rem = idx & 511;
    int col = rem >> 3;
    int ch8 = (rem & 7) << 3;
    int h = h0 - 1 + row;
    s0[i] = {0.f, 0.f, 0.f, 0.f};
    s1[i] = {0.f, 0.f, 0.f, 0.f};
    if ((unsigned)h < 64u) {
      const float* p = xb + ((h * 64 + col) * 64 + ch8);
      s0[i] = *(const float4*)p;
      s1[i] = *(const float4*)(p + 4);
    }
  }

  // ---- B fragment loader: direct from w (replaces wfragg) ----
  // wb[nb] = &w[(nb*16 + l15)*LIN + q*8]; fragment(step) at wb + tap*63 + half*32.
  const float* wb[4];
#pragma unroll
  for (int nb = 0; nb < 4; ++nb) wb[nb] = w + (nb * 16 + l15) * LIN + q * 8;

  auto loadB = [&](int step, short8v* dst) {
    const int tap = step >> 1, half = step & 1;
#pragma unroll
    for (int nb = 0; nb < 4; ++nb) {
      const float* p = wb[nb] + tap * 63 + half * 32;
      float f0 = p[0];
      if (half == 0) f0 = (q == 0) ? 0.0f : f0;   // c==0 time column -> 0
      uint4v o;
      o[0] = cvt_pk_bf16(f0,   p[1]);
      o[1] = cvt_pk_bf16(p[2], p[3]);
      o[2] = cvt_pk_bf16(p[4], p[5]);
      o[3] = cvt_pk_bf16(p[6], p[7]);
      dst[nb] = __builtin_bit_cast(short8v, o);
    }
  };

  // ---- early issue: B fragments for steps 0..2 + epilogue constants ----
  short8v b0[4], b1[4], b2[4];
  loadB(0, b0);
  loadB(1, b1);
  loadB(2, b2);
  float bj[4], w0j[4];
#pragma unroll
  for (int nb = 0; nb < 4; ++nb) {
    int n = nb * 16 + l15;
    bj[nb] = bias[n];
    w0j[nb] = w[n * LIN];   // weight[:,0] fp32
  }

  // ---- phase-1 convert+write: LDS rows 0..3 (x rows h0-1..h0+2) ----
#pragma unroll
  for (int i = 0; i < 8; ++i) {
    int idx = i * 256 + tid;
    int row = idx >> 9;
    int rem = idx & 511;
    int col = rem >> 3;
    int ch8 = (rem & 7) << 3;
    uint4v o;
    o[0] = cvt_pk_bf16(s0[i].x, s0[i].y);
    o[1] = cvt_pk_bf16(s0[i].z, s0[i].w);
    o[2] = cvt_pk_bf16(s1[i].x, s1[i].y);
    o[3] = cvt_pk_bf16(s1[i].z, s1[i].w);
    *(uint4v*)&xt[(row * 66 + col + 1) * 72 + ch8] = o;
  }
  if (tid < 64) {   // pads for rows 0..3, cols 0 and 65
    int r = tid >> 4;
    int cc = (tid >> 3) & 1;
    int ch8 = (tid & 7) << 3;
    short8v z = {0, 0, 0, 0, 0, 0, 0, 0};
    *(short8v*)&xt[(r * 66 + cc * 65) * 72 + ch8] = z;
  }
  __syncthreads();   // rows 0..3 visible -> kh=0 taps computable for all waves

  floatx4 acc[4][4];
#pragma unroll
  for (int mb = 0; mb < 4; ++mb)
#pragma unroll
    for (int nb = 0; nb < 4; ++nb) acc[mb][nb] = floatx4{0.f, 0.f, 0.f, 0.f};

  auto do_step = [&](int step) {
    const int tap = step >> 1, half = step & 1;
    const int kh = tap / 3, kw = tap % 3;

    short8v bn[4];
    if (step + 3 < 18) loadB(step + 3, bn);

    const short* ab = &xt[((wv + kh) * 66 + kw + l15) * 72 + half * 32 + q * 8];
    short8v a[4];
#pragma unroll
    for (int mb = 0; mb < 4; ++mb)
      a[mb] = *(const short8v*)(ab + mb * 16 * 72);

#pragma unroll
    for (int mb = 0; mb < 4; ++mb) {
#pragma unroll
      for (int nb = 0; nb < 4; ++nb)
        acc[mb][nb] = __builtin_amdgcn_mfma_f32_16x16x32_bf16(a[mb], b0[nb], acc[mb][nb], 0, 0, 0);
    }
#pragma unroll
    for (int nb = 0; nb < 4; ++nb) { b0[nb] = b1[nb]; b1[nb] = b2[nb]; b2[nb] = bn[nb]; }
  };

  // kh=0 taps (steps 0..5): only need LDS rows 0..3
#pragma unroll
  for (int step = 0; step < 6; ++step) do_step(step);

  // ---- phase-2 write-late: LDS rows 4..5 (loads issued at top, long complete) ----
#pragma unroll
  for (int i = 8; i < 12; ++i) {
    int idx = i * 256 + tid;
    int row = idx >> 9;
    int rem = idx & 511;
    int col = rem >> 3;
    int ch8 = (rem & 7) << 3;
    uint4v o;
    o[0] = cvt_pk_bf16(s0[i].x, s0[i].y);
    o[1] = cvt_pk_bf16(s0[i].z, s0[i].w);
    o[2] = cvt_pk_bf16(s1[i].x, s1[i].y);
    o[3] = cvt_pk_bf16(s1[i].z, s1[i].w);
    *(uint4v*)&xt[(row * 66 + col + 1) * 72 + ch8] = o;
  }
  if (tid < 32) {   // pads for rows 4..5
    int r = 4 + (tid >> 4);
    int cc = (tid >> 3) & 1;
    int ch8 = (tid & 7) << 3;
    short8v z = {0, 0, 0, 0, 0, 0, 0, 0};
    *(short8v*)&xt[(r * 66 + cc * 65) * 72 + ch8] = z;
  }
  __syncthreads();   // rows 4..5 visible

#pragma unroll
  for (int step = 6; step < 18; ++step) do_step(step);

  // ---- per-pixel time feature (this wave's row; lane <-> pixel col) ----
  {
    float ss = 0.f;
#pragma unroll
    for (int dh = 0; dh < 3; ++dh)
#pragma unroll
      for (int dw = 0; dw < 3; ++dw) {
        float tv = bf16_to_f32(xt[((wv + dh) * 66 + lane + dw) * 72]);
        tv = fmaxf(tv, 1.0f);
        ss += tv * tv;
      }
    tres_s[wv * 64 + lane] = sqrtf(ss - 8.0f);   // same-wave producer/consumer
  }

  __syncthreads();   // last xt read done (all waves) -> safe to alias as ostg

  // ---- epilogue: bias + rank-1 time term, Lorentz norm (DPP), scatter to LDS ----
  float* ostg = (float*)shmem + wv * 4160;   // this wave's 64px x 65ch row image
#pragma unroll
  for (int mb = 0; mb < 4; ++mb) {
    float4 t4 = *(const float4*)&tres_s[wv * 64 + mb * 16 + q * 4];
#pragma unroll
    for (int r = 0; r < 4; ++r) {
      int pcol = mb * 16 + q * 4 + r;      // C/D row m = quad*4 + reg
      float tr = t4[r];
      float v0 = acc[mb][0][r] + bj[0] + tr * w0j[0];
      float v1 = acc[mb][1][r] + bj[1] + tr * w0j[1];
      float v2 = acc[mb][2][r] + bj[2] + tr * w0j[2];
      float v3 = acc[mb][3][r] + bj[3] + tr * w0j[3];
      float ss = v0 * v0 + v1 * v1 + v2 * v2 + v3 * v3;
      ss = dpp_add<0xB1>(ss);    // + lane^1
      ss = dpp_add<0x4E>(ss);    // + lane^2
      ss = dpp_add<0x141>(ss);   // + mirror-8
      ss = dpp_add<0x140>(ss);   // + mirror-16 (full 16-lane sum)
      float* pb = ostg + pcol * 65;
      if (l15 == 0) pb[0] = sqrtf(ss + 1.0f);
      pb[1 + l15]  = v0;
      pb[17 + l15] = v1;
      pb[33 + l15] = v2;
      pb[49 + l15] = v3;
    }
  }

  // ---- coalesced flush: LDS row image -> global (dense dwordx4) ----
  // Same-wave produce/consume: compiler inserts the lgkmcnt wait; no barrier.
  {
    float* orow = out + (size_t)((bb * 64 + h0 + wv) * 64) * 65;
#pragma unroll
    for (int it = 0; it < 16; ++it) {
      int off = it * 256 + lane * 4;
      *(float4*)(orow + off) = *(const float4*)(ostg + off);
    }
    if (lane < 16) {   // remainder: 4160 - 4096 = 64 floats
      int off = 4096 + lane * 4;
      *(float4*)(orow + off) = *(const float4*)(ostg + off);
    }
  }
}

extern "C" void kernel_launch(void* const* d_in, const int* in_sizes, int n_in,
                              void* d_out, int out_size, void* d_ws, size_t ws_size,
                              hipStream_t stream) {
  const float* x = (const float*)d_in[0];
  const float* w = (const float*)d_in[1];
  const float* b = (const float*)d_in[2];
  float* out = (float*)d_out;
  (void)d_ws; (void)ws_size;   // workspace no longer used: prep kernel fused away

  lconv_main<<<32 * 16, 256, 0, stream>>>(x, w, b, out);
}

// Round 15
// 96.655 us; speedup vs baseline: 1.1252x; 1.1252x over previous
//
#include <hip/hip_runtime.h>
#include <cstdint>
#include <cstddef>

typedef __attribute__((ext_vector_type(8))) short short8v;
typedef __attribute__((ext_vector_type(4))) unsigned uint4v;
typedef __attribute__((ext_vector_type(4))) float floatx4;

#define LIN 568   // weight row length: 1 + 9*63

__device__ __forceinline__ short f32_to_bf16(float f) {
  unsigned u = __builtin_bit_cast(unsigned, f);
  u += 0x7fffu + ((u >> 16) & 1u);   // RNE (inputs finite)
  return (short)(u >> 16);
}
__device__ __forceinline__ float bf16_to_f32(short s) {
  return __builtin_bit_cast(float, ((unsigned)(unsigned short)s) << 16);
}
// Packed RNE f32->bf16 (2 values / instruction), bitwise-identical to manual RNE.
__device__ __forceinline__ unsigned cvt_pk_bf16(float lo, float hi) {
  unsigned r;
  asm("v_cvt_pk_bf16_f32 %0, %1, %2" : "=v"(r) : "v"(lo), "v"(hi));
  return r;
}
// Cross-lane add via DPP (pure VALU, no ds op).
template<int CTRL>
__device__ __forceinline__ float dpp_add(float v) {
  int y = __builtin_amdgcn_update_dpp(0, __builtin_bit_cast(int, v), CTRL, 0xF, 0xF, true);
  return v + __builtin_bit_cast(float, y);
}

// Pack weight into MFMA-B-fragment-major order (bf16):
//   wfragg[step*2048 + nb*512 + lane*8 + j]
//     = W[n = nb*16 + (lane&15)][k = tap*64 + half*32 + (lane>>4)*8 + j]
// step = tap*2 + half; c==0 column zeroed (time feature is rank-1 epilogue).
__global__ void prep_weight(const float* __restrict__ w, short* __restrict__ wfragg) {
  int i = blockIdx.x * 256 + threadIdx.x;   // 0 .. 36863
  if (i >= 9 * 2 * 4 * 64 * 8) return;
  int j    = i & 7;
  int lane = (i >> 3) & 63;
  int nb   = (i >> 9) & 3;
  int half = (i >> 11) & 1;
  int tap  = i >> 12;
  int n = nb * 16 + (lane & 15);
  int c = half * 32 + ((lane >> 4) << 3) + j;
  float v = (c == 0) ? 0.0f : w[n * LIN + 1 + tap * 63 + (c - 1)];
  wfragg[i] = f32_to_bf16(v);
}

// CHAMPION (R8, 95.58 us): R4 structure + DPP Lorentz reduce + LDS-staged
// coalesced output flush. Restored verbatim after R9-R14 falsified every
// further structural lever (A-dbuf, n-split, rolled code, B-through-LDS,
// single-phase staging, prep fusion — all neutral or regressions).
__launch_bounds__(256, 2)
__global__ void lconv_main(const float* __restrict__ x, const float* __restrict__ w,
                           const float* __restrict__ bias, const short* __restrict__ wfragg,
                           float* __restrict__ out) {
  // 66560 B: holds short xt[6*66*72] (57024 B) during compute, then aliased as
  // float ostg[4][4160] (66560 B) for the store-staging epilogue.
  __shared__ __align__(16) char shmem[4 * 4160 * 4];
  __shared__ float tres_s[4 * 64];    // per-wave time-feature row (1 KB)
  short* xt = (short*)shmem;

  const int tid = threadIdx.x;
  const int bb = blockIdx.x >> 4;          // batch 0..31
  const int h0 = (blockIdx.x & 15) << 2;   // first output row of 4-row strip
  const float* xb = x + (size_t)bb * (64 * 64 * 64);

  const int lane = tid & 63;
  const int l15 = lane & 15;
  const int q = lane >> 4;
  const int wv = tid >> 6;   // wave id = strip row

  // ---- issue ALL staging loads up front (T14 issue-early) ----
  float4 s0[12], s1[12];
#pragma unroll
  for (int i = 0; i < 12; ++i) {
    int idx = i * 256 + tid;       // 0..3071 : rows 0..5 x 64 cols x 8 ch8-groups
    int row = idx >> 9;
    int rem = idx & 511;
    int col = rem >> 3;
    int ch8 = (rem & 7) << 3;
    int h = h0 - 1 + row;
    s0[i] = {0.f, 0.f, 0.f, 0.f};
    s1[i] = {0.f, 0.f, 0.f, 0.f};
    if ((unsigned)h < 64u) {
      const float* p = xb + ((h * 64 + col) * 64 + ch8);
      s0[i] = *(const float4*)p;
      s1[i] = *(const float4*)(p + 4);
    }
  }

  // ---- early issue: B fragments for steps 0..2 + epilogue constants ----
  const short* wfl = wfragg + lane * 8;
  short8v b0[4], b1[4], b2[4];
#pragma unroll
  for (int nb = 0; nb < 4; ++nb) {
    b0[nb] = *(const short8v*)(wfl + 0 * 2048 + nb * 512);
    b1[nb] = *(const short8v*)(wfl + 1 * 2048 + nb * 512);
    b2[nb] = *(const short8v*)(wfl + 2 * 2048 + nb * 512);
  }
  float bj[4], w0j[4];
#pragma unroll
  for (int nb = 0; nb < 4; ++nb) {
    int n = nb * 16 + l15;
    bj[nb] = bias[n];
    w0j[nb] = w[n * LIN];   // weight[:,0] fp32
  }

  // ---- phase-1 convert+write: LDS rows 0..3 (x rows h0-1..h0+2) ----
#pragma unroll
  for (int i = 0; i < 8; ++i) {
    int idx = i * 256 + tid;
    int row = idx >> 9;
    int rem = idx & 511;
    int col = rem >> 3;
    int ch8 = (rem & 7) << 3;
    uint4v o;
    o[0] = cvt_pk_bf16(s0[i].x, s0[i].y);
    o[1] = cvt_pk_bf16(s0[i].z, s0[i].w);
    o[2] = cvt_pk_bf16(s1[i].x, s1[i].y);
    o[3] = cvt_pk_bf16(s1[i].z, s1[i].w);
    *(uint4v*)&xt[(row * 66 + col + 1) * 72 + ch8] = o;
  }
  if (tid < 64) {   // pads for rows 0..3, cols 0 and 65
    int r = tid >> 4;
    int cc = (tid >> 3) & 1;
    int ch8 = (tid & 7) << 3;
    short8v z = {0, 0, 0, 0, 0, 0, 0, 0};
    *(short8v*)&xt[(r * 66 + cc * 65) * 72 + ch8] = z;
  }
  __syncthreads();   // rows 0..3 visible -> kh=0 taps computable for all waves

  floatx4 acc[4][4];
#pragma unroll
  for (int mb = 0; mb < 4; ++mb)
#pragma unroll
    for (int nb = 0; nb < 4; ++nb) acc[mb][nb] = floatx4{0.f, 0.f, 0.f, 0.f};

  auto do_step = [&](int step) {
    const int tap = step >> 1, half = step & 1;
    const int kh = tap / 3, kw = tap % 3;

    short8v bn[4];
    if (step + 3 < 18) {
#pragma unroll
      for (int nb = 0; nb < 4; ++nb)
        bn[nb] = *(const short8v*)(wfl + (step + 3) * 2048 + nb * 512);
    }

    const short* ab = &xt[((wv + kh) * 66 + kw + l15) * 72 + half * 32 + q * 8];
    short8v a[4];
#pragma unroll
    for (int mb = 0; mb < 4; ++mb)
      a[mb] = *(const short8v*)(ab + mb * 16 * 72);

#pragma unroll
    for (int mb = 0; mb < 4; ++mb) {
#pragma unroll
      for (int nb = 0; nb < 4; ++nb)
        acc[mb][nb] = __builtin_amdgcn_mfma_f32_16x16x32_bf16(a[mb], b0[nb], acc[mb][nb], 0, 0, 0);
    }
#pragma unroll
    for (int nb = 0; nb < 4; ++nb) { b0[nb] = b1[nb]; b1[nb] = b2[nb]; b2[nb] = bn[nb]; }
  };

  // kh=0 taps (steps 0..5): only need LDS rows 0..3
#pragma unroll
  for (int step = 0; step < 6; ++step) do_step(step);

  // ---- phase-2 write-late: LDS rows 4..5 (loads issued at top, long complete) ----
#pragma unroll
  for (int i = 8; i < 12; ++i) {
    int idx = i * 256 + tid;
    int row = idx >> 9;
    int rem = idx & 511;
    int col = rem >> 3;
    int ch8 = (rem & 7) << 3;
    uint4v o;
    o[0] = cvt_pk_bf16(s0[i].x, s0[i].y);
    o[1] = cvt_pk_bf16(s0[i].z, s0[i].w);
    o[2] = cvt_pk_bf16(s1[i].x, s1[i].y);
    o[3] = cvt_pk_bf16(s1[i].z, s1[i].w);
    *(uint4v*)&xt[(row * 66 + col + 1) * 72 + ch8] = o;
  }
  if (tid < 32) {   // pads for rows 4..5
    int r = 4 + (tid >> 4);
    int cc = (tid >> 3) & 1;
    int ch8 = (tid & 7) << 3;
    short8v z = {0, 0, 0, 0, 0, 0, 0, 0};
    *(short8v*)&xt[(r * 66 + cc * 65) * 72 + ch8] = z;
  }
  __syncthreads();   // rows 4..5 visible

#pragma unroll
  for (int step = 6; step < 18; ++step) do_step(step);

  // ---- per-pixel time feature (this wave's row; lane <-> pixel col) ----
  {
    float ss = 0.f;
#pragma unroll
    for (int dh = 0; dh < 3; ++dh)
#pragma unroll
      for (int dw = 0; dw < 3; ++dw) {
        float tv = bf16_to_f32(xt[((wv + dh) * 66 + lane + dw) * 72]);
        tv = fmaxf(tv, 1.0f);
        ss += tv * tv;
      }
    tres_s[wv * 64 + lane] = sqrtf(ss - 8.0f);   // same-wave producer/consumer
  }

  __syncthreads();   // last xt read done (all waves) -> safe to alias as ostg

  // ---- epilogue: bias + rank-1 time term, Lorentz norm (DPP), scatter to LDS ----
  float* ostg = (float*)shmem + wv * 4160;   // this wave's 64px x 65ch row image
#pragma unroll
  for (int mb = 0; mb < 4; ++mb) {
    float4 t4 = *(const float4*)&tres_s[wv * 64 + mb * 16 + q * 4];
#pragma unroll
    for (int r = 0; r < 4; ++r) {
      int pcol = mb * 16 + q * 4 + r;      // C/D row m = quad*4 + reg
      float tr = t4[r];
      float v0 = acc[mb][0][r] + bj[0] + tr * w0j[0];
      float v1 = acc[mb][1][r] + bj[1] + tr * w0j[1];
      float v2 = acc[mb][2][r] + bj[2] + tr * w0j[2];
      float v3 = acc[mb][3][r] + bj[3] + tr * w0j[3];
      float ss = v0 * v0 + v1 * v1 + v2 * v2 + v3 * v3;
      ss = dpp_add<0xB1>(ss);    // + lane^1
      ss = dpp_add<0x4E>(ss);    // + lane^2
      ss = dpp_add<0x141>(ss);   // + mirror-8
      ss = dpp_add<0x140>(ss);   // + mirror-16 (full 16-lane sum)
      float* pb = ostg + pcol * 65;
      if (l15 == 0) pb[0] = sqrtf(ss + 1.0f);
      pb[1 + l15]  = v0;
      pb[17 + l15] = v1;
      pb[33 + l15] = v2;
      pb[49 + l15] = v3;
    }
  }

  // ---- coalesced flush: LDS row image -> global (dense dwordx4) ----
  // Same-wave produce/consume: compiler inserts the lgkmcnt wait; no barrier.
  {
    float* orow = out + (size_t)((bb * 64 + h0 + wv) * 64) * 65;
#pragma unroll
    for (int it = 0; it < 16; ++it) {
      int off = it * 256 + lane * 4;
      *(float4*)(orow + off) = *(const float4*)(ostg + off);
    }
    if (lane < 16) {   // remainder: 4160 - 4096 = 64 floats
      int off = 4096 + lane * 4;
      *(float4*)(orow + off) = *(const float4*)(ostg + off);
    }
  }
}

extern "C" void kernel_launch(void* const* d_in, const int* in_sizes, int n_in,
                              void* d_out, int out_size, void* d_ws, size_t ws_size,
                              hipStream_t stream) {
  const float* x = (const float*)d_in[0];
  const float* w = (const float*)d_in[1];
  const float* b = (const float*)d_in[2];
  float* out = (float*)d_out;
  short* wfragg = (short*)d_ws;   // 73728 B fragment-packed bf16 weight

  prep_weight<<<144, 256, 0, stream>>>(w, wfragg);
  lconv_main<<<32 * 16, 256, 0, stream>>>(x, w, b, wfragg, out);
}